// Round 2
// baseline (1894.425 us; speedup 1.0000x reference)
//
#include <hip/hip_runtime.h>
#include <math.h>

#define BATCH 512
#define TT    1024
#define FF    128
#define UU    50
#define ZN    200   // 4*UU
#define RPP   8     // rows per pass in GEMM kernel

__device__ __forceinline__ float sigmoid_fast(float x) {
    return 1.0f / (1.0f + __expf(-x));
}
__device__ __forceinline__ float tanh_fast(float x) {
    float e = __expf(2.0f * x);
    return 1.0f - 2.0f / (e + 1.0f);
}

// ---------------- Kernel A: zx[b,t,j] = x[b,t,:] @ K[:,j] + bias[j] ----------------
// Col-per-thread (j), K column in VGPRs, x rows broadcast from LDS (uniform b128),
// 8 rows per pass with double-buffered staging. launch_bounds(256,1) so the
// compiler has a 512-VGPR budget and will NOT shuffle kreg out of registers.
__launch_bounds__(256, 1)
__global__ void xk_gemm_kernel(const float* __restrict__ x,
                               const float* __restrict__ K,
                               const float* __restrict__ bias,
                               float* __restrict__ zx) {
    const int b = blockIdx.x;
    const int j = threadIdx.x;          // column 0..255 (j<200 active)

    __shared__ __align__(16) float xs[2][RPP * FF];   // 2 x 4 KiB

    float kreg[FF];
    float bj = 0.0f;
    if (j < ZN) {
        #pragma unroll
        for (int k = 0; k < FF; ++k) kreg[k] = K[k * ZN + j];   // coalesced over j
        bj = bias[j];
    }

    const float* xrow = x + (size_t)b * TT * FF;
    float* zrow = zx + (size_t)b * TT * ZN;

    // stage pass 0 (RPP*FF = 1024 floats = 256 float4 = one per thread)
    ((float4*)xs[0])[threadIdx.x] = ((const float4*)xrow)[threadIdx.x];
    __syncthreads();

    const int NPASS = TT / RPP;   // 128
    for (int p = 0; p < NPASS; ++p) {
        const int cur = p & 1, nxt = cur ^ 1;

        // issue next pass's staging load early (latency hides under FMAs)
        float4 gx;
        const bool more = (p + 1) < NPASS;
        if (more) gx = ((const float4*)(xrow + (size_t)(p + 1) * RPP * FF))[threadIdx.x];

        if (j < ZN) {
            float acc[RPP];
            #pragma unroll
            for (int r = 0; r < RPP; ++r) acc[r] = bj;
            const float4* xb = (const float4*)xs[cur];
            #pragma unroll
            for (int k4 = 0; k4 < FF / 4; ++k4) {
                #pragma unroll
                for (int r = 0; r < RPP; ++r) {          // interleaves 8 indep chains
                    float4 xv = xb[r * (FF / 4) + k4];   // uniform broadcast read
                    acc[r] = fmaf(xv.x, kreg[4 * k4 + 0], acc[r]);
                    acc[r] = fmaf(xv.y, kreg[4 * k4 + 1], acc[r]);
                    acc[r] = fmaf(xv.z, kreg[4 * k4 + 2], acc[r]);
                    acc[r] = fmaf(xv.w, kreg[4 * k4 + 3], acc[r]);
                }
            }
            float* zp = zrow + (size_t)p * RPP * ZN + j;
            #pragma unroll
            for (int r = 0; r < RPP; ++r) zp[r * ZN] = acc[r];   // coalesced over j
        }

        if (more) ((float4*)xs[nxt])[threadIdx.x] = gx;   // write-late (waits vmcnt here)
        __syncthreads();
    }
}

// ---------------- Kernel B: the sequential scan, h@R only (50-wide) ----------------
// One batch per block. One barrier per step: gates replicated in every wave
// (reading the barrier'd z from LDS), h broadcast wave-locally, z double-buffered.
__launch_bounds__(256, 2)
__global__ void lstm_scan_kernel(const float* __restrict__ zx,
                                 const float* __restrict__ R,
                                 const float* __restrict__ dw,
                                 const float* __restrict__ db,
                                 float* __restrict__ out) {
    const int b = blockIdx.x;
    const int tid = threadIdx.x;
    const int w = tid >> 6;        // wave id 0..3
    const int l = tid & 63;        // lane in wave

    __shared__ __align__(16) float zs[2][ZN];   // double-buffered pre-activations
    __shared__ __align__(16) float hs[4][52];   // per-wave h copy (52 pad for b128)

    float rreg[52];
    if (tid < ZN) {
        #pragma unroll
        for (int k = 0; k < UU; ++k) rreg[k] = R[k * ZN + tid];
        rreg[50] = 0.0f; rreg[51] = 0.0f;
    }

    const float* zp = zx + (size_t)b * TT * ZN;

    // t=0: z(0) = zx(0) (h(-1)=0)
    if (tid < ZN) zs[0][tid] = zp[tid];
    if (l < 52) hs[w][l] = 0.0f;
    float c = 0.0f;                 // cell state, replicated per wave (lanes l<UU)
    __syncthreads();

    float pref = (tid < ZN) ? zp[ZN + tid] : 0.0f;   // zx(1)

    int cur = 0;
    for (int t = 1; t < TT; ++t) {
        // depth-1 prefetch of zx(t+1) (clamped at the end; redundant load is harmless)
        const int tn = (t + 1 < TT) ? (t + 1) : (TT - 1);
        float pnext = 0.0f;
        if (tid < ZN) pnext = zp[(size_t)tn * ZN + tid];

        // phase 1: gates of step t-1, replicated in every wave (wave-local, no barrier)
        if (l < UU) {
            float zi = zs[cur][l];
            float zf = zs[cur][l + UU];
            float zg = zs[cur][l + 2 * UU];
            float zo = zs[cur][l + 3 * UU];
            float gi = sigmoid_fast(zi);
            float gf = sigmoid_fast(zf);
            float go = sigmoid_fast(zo);
            float gg = tanh_fast(zg);
            c = gf * c + gi * gg;
            hs[w][l] = go * tanh_fast(c);
        }

        // phase 2: z(t) = zx(t) + h(t-1) @ R   (reads own wave's hs — lockstep-safe)
        if (tid < ZN) {
            float a0 = pref, a1 = 0.0f, a2 = 0.0f, a3 = 0.0f;
            const float4* h4 = (const float4*)hs[w];
            #pragma unroll
            for (int k4 = 0; k4 < 13; ++k4) {
                float4 hv = h4[k4];
                a0 = fmaf(hv.x, rreg[4 * k4 + 0], a0);
                a1 = fmaf(hv.y, rreg[4 * k4 + 1], a1);
                a2 = fmaf(hv.z, rreg[4 * k4 + 2], a2);
                a3 = fmaf(hv.w, rreg[4 * k4 + 3], a3);
            }
            zs[cur ^ 1][tid] = (a0 + a1) + (a2 + a3);
        }

        pref = pnext;
        cur ^= 1;
        __syncthreads();
    }

    // epilogue: final gates (step TT-1) + dense head, wave 0 only
    if (w == 0) {
        if (l < UU) {
            float zi = zs[cur][l];
            float zf = zs[cur][l + UU];
            float zg = zs[cur][l + 2 * UU];
            float zo = zs[cur][l + 3 * UU];
            float gi = sigmoid_fast(zi);
            float gf = sigmoid_fast(zf);
            float go = sigmoid_fast(zo);
            float gg = tanh_fast(zg);
            c = gf * c + gi * gg;
            hs[0][l] = go * tanh_fast(c);
        }
        if (l == 0) {
            float s = db[0];
            for (int u = 0; u < UU; ++u) s = fmaf(hs[0][u], dw[u], s);
            out[b] = s;
        }
    }
}

// ---------------- Fallback (round-1 monolithic kernel) if ws is too small ----------
__launch_bounds__(256, 2)
__global__ void lstm_fused_kernel(const float* __restrict__ x,
                                  const float* __restrict__ K,
                                  const float* __restrict__ R,
                                  const float* __restrict__ bias,
                                  const float* __restrict__ dw,
                                  const float* __restrict__ db,
                                  float* __restrict__ out) {
    const int b = blockIdx.x;
    const int j = threadIdx.x;

    __shared__ __align__(16) float xs[2][FF];
    __shared__ __align__(16) float zs[ZN];
    __shared__ __align__(16) float hs[52];

    float kreg[FF];
    float rreg[52];
    float bj = 0.0f;
    if (j < ZN) {
        #pragma unroll
        for (int k = 0; k < FF; ++k) kreg[k] = K[k * ZN + j];
        #pragma unroll
        for (int k = 0; k < UU; ++k) rreg[k] = R[k * ZN + j];
        rreg[50] = 0.0f; rreg[51] = 0.0f;
        bj = bias[j];
    }
    if (j < 52) hs[j] = 0.0f;
    float c = 0.0f;

    const float* xrow = x + (size_t)b * TT * FF;
    if (j < FF) xs[0][j] = xrow[j];
    __syncthreads();

    for (int t = 0; t < TT; ++t) {
        const int cur = t & 1, nxt = cur ^ 1;
        float xnext = 0.0f;
        if ((t + 1) < TT && j < FF) xnext = xrow[(size_t)(t + 1) * FF + j];

        if (j < ZN) {
            float a0 = bj, a1 = 0.0f, a2 = 0.0f, a3 = 0.0f;
            const float4* x4 = (const float4*)xs[cur];
            #pragma unroll
            for (int kk = 0; kk < FF / 4; ++kk) {
                float4 xv = x4[kk];
                a0 = fmaf(xv.x, kreg[4 * kk + 0], a0);
                a1 = fmaf(xv.y, kreg[4 * kk + 1], a1);
                a2 = fmaf(xv.z, kreg[4 * kk + 2], a2);
                a3 = fmaf(xv.w, kreg[4 * kk + 3], a3);
            }
            const float4* h4 = (const float4*)hs;
            #pragma unroll
            for (int kk = 0; kk < 13; ++kk) {
                float4 hv = h4[kk];
                a0 = fmaf(hv.x, rreg[4 * kk + 0], a0);
                a1 = fmaf(hv.y, rreg[4 * kk + 1], a1);
                a2 = fmaf(hv.z, rreg[4 * kk + 2], a2);
                a3 = fmaf(hv.w, rreg[4 * kk + 3], a3);
            }
            zs[j] = (a0 + a1) + (a2 + a3);
        }
        __syncthreads();

        if (j < UU) {
            float zi = zs[j];
            float zf = zs[j + UU];
            float zg = zs[j + 2 * UU];
            float zo = zs[j + 3 * UU];
            float fi = sigmoid_fast(zi);
            float ff = sigmoid_fast(zf);
            float fo = sigmoid_fast(zo);
            float tg = tanh_fast(zg);
            c = ff * c + fi * tg;
            hs[j] = fo * tanh_fast(c);
        }
        if ((t + 1) < TT && j < FF) xs[nxt][j] = xnext;
        __syncthreads();
    }

    if (j == 0) {
        float s = db[0];
        #pragma unroll
        for (int u = 0; u < UU; ++u) s = fmaf(hs[u], dw[u], s);
        out[b] = s;
    }
}

extern "C" void kernel_launch(void* const* d_in, const int* in_sizes, int n_in,
                              void* d_out, int out_size, void* d_ws, size_t ws_size,
                              hipStream_t stream) {
    const float* x    = (const float*)d_in[0];  // [512,1024,128]
    const float* K    = (const float*)d_in[1];  // [128,200]
    const float* R    = (const float*)d_in[2];  // [50,200]
    const float* bias = (const float*)d_in[3];  // [200]
    const float* dw   = (const float*)d_in[4];  // [50,1]
    const float* db   = (const float*)d_in[5];  // [1]
    float* out = (float*)d_out;                 // [512,1]

    const size_t zx_bytes = (size_t)BATCH * TT * ZN * sizeof(float);  // 420 MB
    if (ws_size >= zx_bytes) {
        float* zx = (float*)d_ws;
        xk_gemm_kernel<<<BATCH, 256, 0, stream>>>(x, K, bias, zx);
        lstm_scan_kernel<<<BATCH, 256, 0, stream>>>(zx, R, dw, db, out);
    } else {
        lstm_fused_kernel<<<BATCH, 256, 0, stream>>>(x, K, R, bias, dw, db, out);
    }
}

// Round 3
// 1412.781 us; speedup vs baseline: 1.3409x; 1.3409x over previous
//
#include <hip/hip_runtime.h>
#include <math.h>

#define BATCH 512
#define TT    1024
#define FF    128
#define UU    50
#define ZN    200          // 4*UU
#define NP    208          // padded N (13 * 16)
#define NT    13           // N tiles of 16
#define MROWS (BATCH * TT) // 524288
#define BM    128          // rows per GEMM block
#define RPP   8            // rows per pass in fallback GEMM

typedef __attribute__((ext_vector_type(8))) short bhalf8;
typedef __attribute__((ext_vector_type(4))) short bhalf4;
typedef __attribute__((ext_vector_type(4))) float f32x4;

__device__ __forceinline__ float sigmoid_fast(float x) {
    return 1.0f / (1.0f + __expf(-x));
}
__device__ __forceinline__ float tanh_fast(float x) {
    float e = __expf(2.0f * x);
    return 1.0f - 2.0f / (e + 1.0f);
}
__device__ __forceinline__ unsigned short bf16_rtn(float x) {
    unsigned int u = __float_as_uint(x);
    unsigned int r = u + 0x7FFFu + ((u >> 16) & 1u);
    return (unsigned short)(r >> 16);
}
__device__ __forceinline__ float bf16_f32(unsigned short h) {
    return __uint_as_float(((unsigned int)h) << 16);
}

// ---------------- Prep: Kt_hi/Kt_lo[NP][FF] bf16 (transposed, hi/lo split) -------
__global__ void prep_kt_kernel(const float* __restrict__ K,
                               unsigned short* __restrict__ kt_hi,
                               unsigned short* __restrict__ kt_lo) {
    const int c = threadIdx.x;          // column 0..255 (c<NP active)
    if (c >= NP) return;
    for (int k = 0; k < FF; ++k) {
        float v = (c < ZN) ? K[k * ZN + c] : 0.0f;
        unsigned short h = bf16_rtn(v);
        float lo = v - bf16_f32(h);
        kt_hi[c * FF + k] = h;
        kt_lo[c * FF + k] = bf16_rtn(lo);
    }
}

// ---------------- Kernel A: zx[m, j] = x[m, :] @ K[:, j] + bias[j] via MFMA ------
// bf16x2 split (hi*hi + hi*lo + lo*hi) for ~fp32 accuracy at bf16 MFMA rate.
// Block: 256 thr (4 waves), 128 rows. x staged reg->LDS as hi/lo bf16 planes with
// XOR swizzle (G4: row-major stride-256B tiles are 16-way conflicts without it).
__launch_bounds__(256, 2)
__global__ void xk_mfma_kernel(const float* __restrict__ x,
                               const unsigned short* __restrict__ kt_hi,
                               const unsigned short* __restrict__ kt_lo,
                               const float* __restrict__ bias,
                               float* __restrict__ zx) {
    __shared__ __align__(16) char xlds[2 * BM * FF * 2];   // hi plane @0, lo @32768

    const int tid = threadIdx.x;
    const size_t rowbase = (size_t)blockIdx.x * BM;
    const float* xb = x + rowbase * FF;

    // ---- stage: coalesced float4 reads, hi/lo split, swizzled b64 LDS writes ----
    const float4* gx = (const float4*)xb;
    #pragma unroll
    for (int i = 0; i < 16; ++i) {
        float4 v = gx[tid + 256 * i];
        const int fidx = (tid + 256 * i) * 4;    // flat float index in 128x128 tile
        const int row = fidx >> 7;
        const int col = fidx & 127;
        unsigned short h0 = bf16_rtn(v.x), h1 = bf16_rtn(v.y),
                       h2 = bf16_rtn(v.z), h3 = bf16_rtn(v.w);
        bhalf4 hv = { (short)h0, (short)h1, (short)h2, (short)h3 };
        bhalf4 lv = { (short)bf16_rtn(v.x - bf16_f32(h0)),
                      (short)bf16_rtn(v.y - bf16_f32(h1)),
                      (short)bf16_rtn(v.z - bf16_f32(h2)),
                      (short)bf16_rtn(v.w - bf16_f32(h3)) };
        const unsigned byte = (unsigned)((row << 8) + (col << 1)) ^ (((unsigned)row & 7u) << 4);
        *(bhalf4*)(xlds + byte)         = hv;
        *(bhalf4*)(xlds + 32768 + byte) = lv;
    }
    __syncthreads();

    // ---- MFMA: wave w owns rows [w*32, w*32+32), all 13 N-tiles ----
    const int w = tid >> 6, l = tid & 63;
    const int lrow = l & 15;
    const int lk   = (l >> 4) << 3;       // k-chunk base (contiguous 8)

    float bv[NT];
    #pragma unroll
    for (int nt = 0; nt < NT; ++nt) {
        const int cidx = nt * 16 + lrow;
        bv[nt] = (cidx < ZN) ? bias[cidx] : 0.0f;
    }

    f32x4 acc0[NT], acc1[NT];
    #pragma unroll
    for (int nt = 0; nt < NT; ++nt) { acc0[nt] = (f32x4)0.0f; acc1[nt] = (f32x4)0.0f; }

    #pragma unroll
    for (int ks = 0; ks < 4; ++ks) {
        const int kbyte = (ks * 32 + lk) * 2;
        const int row0 = (w << 5) + lrow;          // rowgroup 0
        const int row1 = row0 + 16;                // rowgroup 1
        const unsigned b0 = (unsigned)((row0 << 8) + kbyte) ^ (((unsigned)row0 & 7u) << 4);
        const unsigned b1 = (unsigned)((row1 << 8) + kbyte) ^ (((unsigned)row1 & 7u) << 4);
        bhalf8 aH0 = *(const bhalf8*)(xlds + b0);
        bhalf8 aL0 = *(const bhalf8*)(xlds + 32768 + b0);
        bhalf8 aH1 = *(const bhalf8*)(xlds + b1);
        bhalf8 aL1 = *(const bhalf8*)(xlds + 32768 + b1);
        #pragma unroll
        for (int nt = 0; nt < NT; ++nt) {
            const int col = nt * 16 + lrow;
            const size_t koff = ((size_t)col << 7) + (size_t)(ks * 32 + lk);
            bhalf8 bH = *(const bhalf8*)(kt_hi + koff);
            bhalf8 bL = *(const bhalf8*)(kt_lo + koff);
            acc0[nt] = __builtin_amdgcn_mfma_f32_16x16x32_bf16(aH0, bH, acc0[nt], 0, 0, 0);
            acc0[nt] = __builtin_amdgcn_mfma_f32_16x16x32_bf16(aH0, bL, acc0[nt], 0, 0, 0);
            acc0[nt] = __builtin_amdgcn_mfma_f32_16x16x32_bf16(aL0, bH, acc0[nt], 0, 0, 0);
            acc1[nt] = __builtin_amdgcn_mfma_f32_16x16x32_bf16(aH1, bH, acc1[nt], 0, 0, 0);
            acc1[nt] = __builtin_amdgcn_mfma_f32_16x16x32_bf16(aH1, bL, acc1[nt], 0, 0, 0);
            acc1[nt] = __builtin_amdgcn_mfma_f32_16x16x32_bf16(aL1, bH, acc1[nt], 0, 0, 0);
        }
    }

    // ---- epilogue: D mapping col=l&15, row=(l>>4)*4+r (m89-verified) ----
    const int rsub = (l >> 4) << 2;
    #pragma unroll
    for (int nt = 0; nt < NT; ++nt) {
        const int col = nt * 16 + lrow;
        if (col < ZN) {
            #pragma unroll
            for (int r = 0; r < 4; ++r) {
                const size_t grow0 = rowbase + (w << 5) + rsub + r;
                zx[grow0 * ZN + col] = acc0[nt][r] + bv[nt];
                const size_t grow1 = grow0 + 16;
                zx[grow1 * ZN + col] = acc1[nt][r] + bv[nt];
            }
        }
    }
}

// ---------------- Kernel B: sequential scan with 8-deep zx prefetch --------------
#define LSTM_STEP(V, CUR) do {                                                      \
    if (l < UU) {                                                                   \
        float zi = zs[CUR][l];                                                      \
        float zf = zs[CUR][l + UU];                                                 \
        float zg = zs[CUR][l + 2 * UU];                                             \
        float zo = zs[CUR][l + 3 * UU];                                             \
        float gi = sigmoid_fast(zi);                                                \
        float gf = sigmoid_fast(zf);                                                \
        float go = sigmoid_fast(zo);                                                \
        float gg = tanh_fast(zg);                                                   \
        c = gf * c + gi * gg;                                                       \
        hs[w][l] = go * tanh_fast(c);                                               \
    }                                                                               \
    if (tid < ZN) {                                                                 \
        float a0 = (V), a1 = 0.0f, a2 = 0.0f, a3 = 0.0f;                            \
        const float4* h4 = (const float4*)hs[w];                                    \
        _Pragma("unroll")                                                           \
        for (int k4 = 0; k4 < 13; ++k4) {                                           \
            float4 hv = h4[k4];                                                     \
            a0 = fmaf(hv.x, rreg[4 * k4 + 0], a0);                                  \
            a1 = fmaf(hv.y, rreg[4 * k4 + 1], a1);                                  \
            a2 = fmaf(hv.z, rreg[4 * k4 + 2], a2);                                  \
            a3 = fmaf(hv.w, rreg[4 * k4 + 3], a3);                                  \
        }                                                                           \
        zs[(CUR) ^ 1][tid] = (a0 + a1) + (a2 + a3);                                 \
    }                                                                               \
    __syncthreads();                                                                \
} while (0)

__launch_bounds__(256, 2)
__global__ void lstm_scan_kernel(const float* __restrict__ zx,
                                 const float* __restrict__ R,
                                 const float* __restrict__ dw,
                                 const float* __restrict__ db,
                                 float* __restrict__ out) {
    const int b = blockIdx.x;
    const int tid = threadIdx.x;
    const int w = tid >> 6;
    const int l = tid & 63;

    __shared__ __align__(16) float zs[2][ZN];
    __shared__ __align__(16) float hs[4][56];   // 56: keeps hs[w] 16B-aligned

    float rreg[52];
    if (tid < ZN) {
        #pragma unroll
        for (int k = 0; k < UU; ++k) rreg[k] = R[k * ZN + tid];
        rreg[50] = 0.0f; rreg[51] = 0.0f;
    }

    const float* zp = zx + (size_t)b * TT * ZN;
    if (tid < ZN) zs[0][tid] = zp[tid];          // z(0) = zx(0)
    if (l < 56) hs[w][l] = 0.0f;
    float c = 0.0f;
    __syncthreads();

    // 8-deep prefetch pipeline: pipe[i] holds zx(s) for upcoming steps
    float pipe[8];
    #pragma unroll
    for (int i = 0; i < 8; ++i)
        pipe[i] = (tid < ZN) ? zp[(size_t)(1 + i) * ZN + tid] : 0.0f;

    // main: 127 groups x 8 steps, s = 1..1016 (parity returns to 0 each group)
    for (int g = 0; g < 127; ++g) {
        #pragma unroll
        for (int q = 0; q < 8; ++q) {
            const int s = (g << 3) + 1 + q;
            float v = pipe[q];
            int sn = s + 8; if (sn > TT - 1) sn = TT - 1;   // clamp (dup load unused)
            if (tid < ZN) pipe[q] = zp[(size_t)sn * ZN + tid];
            LSTM_STEP(v, (q & 1));
        }
    }
    // remainder: s = 1017..1023 consuming pipe[0..6]
    {
        float v;
        v = pipe[0]; LSTM_STEP(v, 0);
        v = pipe[1]; LSTM_STEP(v, 1);
        v = pipe[2]; LSTM_STEP(v, 0);
        v = pipe[3]; LSTM_STEP(v, 1);
        v = pipe[4]; LSTM_STEP(v, 0);
        v = pipe[5]; LSTM_STEP(v, 1);
        v = pipe[6]; LSTM_STEP(v, 0);
    }

    // epilogue: gates of z(1023) (in zs[1]) + dense head, wave 0 only
    if (w == 0) {
        if (l < UU) {
            float zi = zs[1][l];
            float zf = zs[1][l + UU];
            float zg = zs[1][l + 2 * UU];
            float zo = zs[1][l + 3 * UU];
            float gi = sigmoid_fast(zi);
            float gf = sigmoid_fast(zf);
            float go = sigmoid_fast(zo);
            float gg = tanh_fast(zg);
            c = gf * c + gi * gg;
            hs[0][l] = go * tanh_fast(c);
        }
        if (l == 0) {
            float s = db[0];
            for (int u = 0; u < UU; ++u) s = fmaf(hs[0][u], dw[u], s);
            out[b] = s;
        }
    }
}

// ---------------- Fallback GEMM (round-2, slow but correct) ----------------------
__launch_bounds__(256, 1)
__global__ void xk_gemm_kernel(const float* __restrict__ x,
                               const float* __restrict__ K,
                               const float* __restrict__ bias,
                               float* __restrict__ zx) {
    const int b = blockIdx.x;
    const int j = threadIdx.x;

    __shared__ __align__(16) float xs[2][RPP * FF];

    float kreg[FF];
    float bj = 0.0f;
    if (j < ZN) {
        #pragma unroll
        for (int k = 0; k < FF; ++k) kreg[k] = K[k * ZN + j];
        bj = bias[j];
    }

    const float* xrow = x + (size_t)b * TT * FF;
    float* zrow = zx + (size_t)b * TT * ZN;

    ((float4*)xs[0])[threadIdx.x] = ((const float4*)xrow)[threadIdx.x];
    __syncthreads();

    const int NPASS = TT / RPP;
    for (int p = 0; p < NPASS; ++p) {
        const int cur = p & 1, nxt = cur ^ 1;
        float4 gxv;
        const bool more = (p + 1) < NPASS;
        if (more) gxv = ((const float4*)(xrow + (size_t)(p + 1) * RPP * FF))[threadIdx.x];

        if (j < ZN) {
            float acc[RPP];
            #pragma unroll
            for (int r = 0; r < RPP; ++r) acc[r] = bj;
            const float4* xb4 = (const float4*)xs[cur];
            #pragma unroll
            for (int k4 = 0; k4 < FF / 4; ++k4) {
                #pragma unroll
                for (int r = 0; r < RPP; ++r) {
                    float4 xv = xb4[r * (FF / 4) + k4];
                    acc[r] = fmaf(xv.x, kreg[4 * k4 + 0], acc[r]);
                    acc[r] = fmaf(xv.y, kreg[4 * k4 + 1], acc[r]);
                    acc[r] = fmaf(xv.z, kreg[4 * k4 + 2], acc[r]);
                    acc[r] = fmaf(xv.w, kreg[4 * k4 + 3], acc[r]);
                }
            }
            float* zpo = zrow + (size_t)p * RPP * ZN + j;
            #pragma unroll
            for (int r = 0; r < RPP; ++r) zpo[r * ZN] = acc[r];
        }
        if (more) ((float4*)xs[nxt])[threadIdx.x] = gxv;
        __syncthreads();
    }
}

// ---------------- Fallback monolithic (round-1) ----------------------------------
__launch_bounds__(256, 2)
__global__ void lstm_fused_kernel(const float* __restrict__ x,
                                  const float* __restrict__ K,
                                  const float* __restrict__ R,
                                  const float* __restrict__ bias,
                                  const float* __restrict__ dw,
                                  const float* __restrict__ db,
                                  float* __restrict__ out) {
    const int b = blockIdx.x;
    const int j = threadIdx.x;

    __shared__ __align__(16) float xs[2][FF];
    __shared__ __align__(16) float zs1[ZN];
    __shared__ __align__(16) float hs1[52];

    float kreg[FF];
    float rreg[52];
    float bj = 0.0f;
    if (j < ZN) {
        #pragma unroll
        for (int k = 0; k < FF; ++k) kreg[k] = K[k * ZN + j];
        #pragma unroll
        for (int k = 0; k < UU; ++k) rreg[k] = R[k * ZN + j];
        rreg[50] = 0.0f; rreg[51] = 0.0f;
        bj = bias[j];
    }
    if (j < 52) hs1[j] = 0.0f;
    float c = 0.0f;

    const float* xrow = x + (size_t)b * TT * FF;
    if (j < FF) xs[0][j] = xrow[j];
    __syncthreads();

    for (int t = 0; t < TT; ++t) {
        const int cur = t & 1, nxt = cur ^ 1;
        float xnext = 0.0f;
        if ((t + 1) < TT && j < FF) xnext = xrow[(size_t)(t + 1) * FF + j];

        if (j < ZN) {
            float a0 = bj, a1 = 0.0f, a2 = 0.0f, a3 = 0.0f;
            const float4* x4 = (const float4*)xs[cur];
            #pragma unroll
            for (int kk = 0; kk < FF / 4; ++kk) {
                float4 xv = x4[kk];
                a0 = fmaf(xv.x, kreg[4 * kk + 0], a0);
                a1 = fmaf(xv.y, kreg[4 * kk + 1], a1);
                a2 = fmaf(xv.z, kreg[4 * kk + 2], a2);
                a3 = fmaf(xv.w, kreg[4 * kk + 3], a3);
            }
            const float4* h4 = (const float4*)hs1;
            #pragma unroll
            for (int kk = 0; kk < 13; ++kk) {
                float4 hv = h4[kk];
                a0 = fmaf(hv.x, rreg[4 * kk + 0], a0);
                a1 = fmaf(hv.y, rreg[4 * kk + 1], a1);
                a2 = fmaf(hv.z, rreg[4 * kk + 2], a2);
                a3 = fmaf(hv.w, rreg[4 * kk + 3], a3);
            }
            zs1[j] = (a0 + a1) + (a2 + a3);
        }
        __syncthreads();

        if (j < UU) {
            float zi = zs1[j];
            float zf = zs1[j + UU];
            float zg = zs1[j + 2 * UU];
            float zo = zs1[j + 3 * UU];
            float fi = sigmoid_fast(zi);
            float ffv = sigmoid_fast(zf);
            float fo = sigmoid_fast(zo);
            float tg = tanh_fast(zg);
            c = ffv * c + fi * tg;
            hs1[j] = fo * tanh_fast(c);
        }
        if ((t + 1) < TT && j < FF) xs[nxt][j] = xnext;
        __syncthreads();
    }

    if (j == 0) {
        float s = db[0];
        #pragma unroll
        for (int u = 0; u < UU; ++u) s = fmaf(hs1[u], dw[u], s);
        out[b] = s;
    }
}

extern "C" void kernel_launch(void* const* d_in, const int* in_sizes, int n_in,
                              void* d_out, int out_size, void* d_ws, size_t ws_size,
                              hipStream_t stream) {
    const float* x    = (const float*)d_in[0];  // [512,1024,128]
    const float* K    = (const float*)d_in[1];  // [128,200]
    const float* R    = (const float*)d_in[2];  // [50,200]
    const float* bias = (const float*)d_in[3];  // [200]
    const float* dw   = (const float*)d_in[4];  // [50,1]
    const float* db   = (const float*)d_in[5];  // [1]
    float* out = (float*)d_out;                 // [512,1]

    const size_t zx_bytes = (size_t)MROWS * ZN * sizeof(float);          // 419.43 MB
    const size_t kt_elems = (size_t)NP * FF;                             // 26624
    const size_t kt_bytes = kt_elems * sizeof(unsigned short);           // 53248

    if (ws_size >= zx_bytes + 2 * kt_bytes) {
        float* zx = (float*)d_ws;
        unsigned short* kt_hi = (unsigned short*)((char*)d_ws + zx_bytes);
        unsigned short* kt_lo = kt_hi + kt_elems;
        prep_kt_kernel<<<1, 256, 0, stream>>>(K, kt_hi, kt_lo);
        xk_mfma_kernel<<<MROWS / BM, 256, 0, stream>>>(x, kt_hi, kt_lo, bias, zx);
        lstm_scan_kernel<<<BATCH, 256, 0, stream>>>(zx, R, dw, db, out);
    } else if (ws_size >= zx_bytes) {
        float* zx = (float*)d_ws;
        xk_gemm_kernel<<<BATCH, 256, 0, stream>>>(x, K, bias, zx);
        lstm_scan_kernel<<<BATCH, 256, 0, stream>>>(zx, R, dw, db, out);
    } else {
        lstm_fused_kernel<<<BATCH, 256, 0, stream>>>(x, K, R, bias, dw, db, out);
    }
}